// Round 8
// baseline (177.371 us; speedup 1.0000x reference)
//
#include <hip/hip_runtime.h>
#include <stdint.h>

#define B_  4
#define T_  2048
#define D_  1024
#define H_  16
#define HD_ 64
#define KK_ 1024

typedef __bf16 bf16_t;
typedef __bf16 bf16x8 __attribute__((ext_vector_type(8)));
typedef float  f32x4  __attribute__((ext_vector_type(4)));
typedef float  f32x16 __attribute__((ext_vector_type(16)));

__device__ __forceinline__ uint16_t f2bf(float f) {
  uint32_t x = __float_as_uint(f);
  uint32_t r = (x + 0x7fffu + ((x >> 16) & 1u)) >> 16;
  return (uint16_t)r;
}

__device__ __forceinline__ uint32_t pack2(float a, float b) {
  return (uint32_t)f2bf(a) | ((uint32_t)f2bf(b) << 16);
}

__device__ __forceinline__ float exp2a(float x) {
  float r;
  asm("v_exp_f32 %0, %1" : "=v"(r) : "v"(x));
  return r;
}

__device__ __forceinline__ uint32_t cvtpk(float a, float b) {
  uint32_t r;
  asm("v_cvt_pk_bf16_f32 %0, %1, %2" : "=v"(r) : "v"(a), "v"(b));
  return r;
}

__device__ __forceinline__ void plswap(uint32_t& a, uint32_t& b) {
  asm("v_permlane32_swap_b32 %0, %1" : "+v"(a), "+v"(b));
}

// async 16B global->LDS; lds dst is wave-uniform base (+lane*16 by HW)
__device__ __forceinline__ void gll16(const void* g, void* l) {
  __builtin_amdgcn_global_load_lds(
      (const __attribute__((address_space(1))) void*)g,
      (__attribute__((address_space(3))) void*)l, 16, 0, 0);
}

// ---------------- fp32 -> bf16 conversion ----------------
__global__ __launch_bounds__(256) void cvt3(const float* __restrict__ s0,
                                            const float* __restrict__ s1,
                                            const float* __restrict__ s2,
                                            uint16_t* __restrict__ d0,
                                            uint16_t* __restrict__ d1,
                                            uint16_t* __restrict__ d2) {
  const float* in = blockIdx.y == 0 ? s0 : (blockIdx.y == 1 ? s1 : s2);
  uint16_t* out = blockIdx.y == 0 ? d0 : (blockIdx.y == 1 ? d1 : d2);
  int i = (blockIdx.x * 256 + threadIdx.x) * 8;
  float4 a = *(const float4*)(in + i);
  float4 b = *(const float4*)(in + i + 4);
  uint4 u;
  u.x = pack2(a.x, a.y);
  u.y = pack2(a.z, a.w);
  u.z = pack2(b.x, b.y);
  u.w = pack2(b.z, b.w);
  *(uint4*)(out + i) = u;
}

__global__ __launch_bounds__(256) void cvtW(const float* __restrict__ s0,
                                            const float* __restrict__ s1,
                                            const float* __restrict__ s2,
                                            const float* __restrict__ s3,
                                            uint16_t* __restrict__ d0,
                                            uint16_t* __restrict__ d1,
                                            uint16_t* __restrict__ d2,
                                            uint16_t* __restrict__ d3) {
  const float* in = blockIdx.y == 0 ? s0 : (blockIdx.y == 1 ? s1 :
                    (blockIdx.y == 2 ? s2 : s3));
  uint16_t* out = blockIdx.y == 0 ? d0 : (blockIdx.y == 1 ? d1 :
                  (blockIdx.y == 2 ? d2 : d3));
  int i = (blockIdx.x * 256 + threadIdx.x) * 8;
  float4 a = *(const float4*)(in + i);
  float4 b = *(const float4*)(in + i + 4);
  uint4 u;
  u.x = pack2(a.x, a.y);
  u.y = pack2(a.z, a.w);
  u.z = pack2(b.x, b.y);
  u.w = pack2(b.z, b.w);
  *(uint4*)(out + i) = u;
}

// ---------------- GEMM: C = A[M,K] @ W[N,K]^T, per-wave 128x64 ----------------
// BMT x 256 tile, BK=64, 8 waves (2M x 4N), per-wave (BMT/2) x 64.
// 2 LDS slots, 1 phase per tile: all frags -> regs, slot dead -> stage t+2
// into it; seam waits counted vmcnt(LPT) (never drains mid-loop).
// mode 0: Q -> bf16 [B,H,T,64] scaled; 1: K same; 2: V -> [B,H,64,T]; 3: fp32.
template <int BMT>
__global__ __launch_bounds__(512, 2)
void gemm256(const uint16_t* __restrict__ a0, const uint16_t* __restrict__ a1,
             const uint16_t* __restrict__ a2, const uint16_t* __restrict__ w0,
             const uint16_t* __restrict__ w1, const uint16_t* __restrict__ w2,
             void* __restrict__ o0, void* __restrict__ o1, void* __restrict__ o2,
             int mode_base, float scale0) {
  constexpr int MF  = BMT / 32;   // m-frags per wave (8 or 4)
  constexpr int ALD = BMT / 64;   // A gll16 per wave per tile (4 or 2)
  constexpr int LPT = ALD + 4;    // loads per wave per tile
  constexpr int BPG = (8192 / BMT) * 4;  // blocks per gemm
  __shared__ __align__(16) uint16_t Ab[2][BMT * 64];
  __shared__ __align__(16) uint16_t Bb[2][256 * 64];

  const int nwg = gridDim.x;
  const int bid = blockIdx.x;
  const int cpx = nwg >> 3;                       // nwg % 8 == 0
  const int swz = (bid & 7) * cpx + (bid >> 3);   // XCD-contiguous chunks
  const int g = swz / BPG;
  const int r = swz % BPG;
  const int mt = r >> 2, nt = r & 3;
  const int m0 = mt * BMT, n0 = nt * 256;

  const uint16_t* A = g == 0 ? a0 : (g == 1 ? a1 : a2);
  const uint16_t* W = g == 0 ? w0 : (g == 1 ? w1 : w2);
  void* Out = g == 0 ? o0 : (g == 1 ? o1 : o2);
  const int mode = mode_base + g;
  const float scale = (mode == 0) ? scale0 : 1.0f;

  const int tid = threadIdx.x;
  const int wid = tid >> 6, lane = tid & 63;
  const int fr = lane & 15, fq = lane >> 4;
  const int wm = wid >> 2, wn = wid & 3;
  const int srow = lane >> 3, c8 = lane & 7;

  f32x4 acc[MF][4];
#pragma unroll
  for (int i = 0; i < MF; ++i)
#pragma unroll
    for (int j = 0; j < 4; ++j) acc[i][j] = (f32x4){0.f, 0.f, 0.f, 0.f};

  const int NT = KK_ / 64;  // 16 tiles

  // LDS row = 64 elems (8 chunks of 8); LDS[row][j] = src[row][j ^ (row&7)].
#define STAGE(s, t)                                                           \
  do {                                                                        \
    _Pragma("unroll")                                                         \
    for (int c = 0; c < ALD; ++c) {                                           \
      int row = wid * (ALD * 8) + c * 8 + srow;                               \
      int sw = (c8 ^ (row & 7)) << 3;                                         \
      gll16(A + (size_t)(m0 + row) * KK_ + (t) * 64 + sw,                     \
            &Ab[s][(wid * (ALD * 8) + c * 8) * 64]);                          \
    }                                                                         \
    _Pragma("unroll")                                                         \
    for (int c = 0; c < 4; ++c) {                                             \
      int row = wid * 32 + c * 8 + srow;                                      \
      int sw = (c8 ^ (row & 7)) << 3;                                         \
      gll16(W + (size_t)(n0 + row) * KK_ + (t) * 64 + sw,                     \
            &Bb[s][(wid * 32 + c * 8) * 64]);                                 \
    }                                                                         \
  } while (0)

  // prologue: stage tiles 0,1; wait tile 0 (LPT = tile 1's loads still flying)
  STAGE(0, 0);
  STAGE(1, 1);
  asm volatile("s_waitcnt vmcnt(%0)" ::"i"(LPT) : "memory");
  __builtin_amdgcn_s_barrier();

  for (int t = 0; t < NT; ++t) {
    const int s = t & 1;
    const uint16_t* Ac = &Ab[s][0];
    const uint16_t* Bc = &Bb[s][0];
    // all frags for this tile -> registers (24 or 16 ds_read_b128)
    bf16x8 af[MF][2], bf[4][2];
#pragma unroll
    for (int mf = 0; mf < MF; ++mf) {
      int ra = wm * (BMT / 2) + mf * 16 + fr;
#pragma unroll
      for (int ks = 0; ks < 2; ++ks)
        af[mf][ks] = *(const bf16x8*)&Ac[ra * 64 + (((ks * 4 + fq) ^ (ra & 7)) << 3)];
    }
#pragma unroll
    for (int nf = 0; nf < 4; ++nf) {
      int rb = wn * 64 + nf * 16 + fr;
#pragma unroll
      for (int ks = 0; ks < 2; ++ks)
        bf[nf][ks] = *(const bf16x8*)&Bc[rb * 64 + (((ks * 4 + fq) ^ (rb & 7)) << 3)];
    }
    // all reads complete block-wide before slot is re-staged
    asm volatile("s_waitcnt lgkmcnt(0)" ::: "memory");
    __builtin_amdgcn_sched_barrier(0);
    __builtin_amdgcn_s_barrier();
    __builtin_amdgcn_sched_barrier(0);
    if (t + 2 < NT) STAGE(s, t + 2);  // slot s is dead; refill for t+2
    __builtin_amdgcn_sched_barrier(0);
    __builtin_amdgcn_s_setprio(1);
#pragma unroll
    for (int ks = 0; ks < 2; ++ks)
#pragma unroll
      for (int mf = 0; mf < MF; ++mf)
#pragma unroll
        for (int nf = 0; nf < 4; ++nf)
          acc[mf][nf] = __builtin_amdgcn_mfma_f32_16x16x32_bf16(af[mf][ks], bf[nf][ks],
                                                                acc[mf][nf], 0, 0, 0);
    __builtin_amdgcn_s_setprio(0);
    if (t + 1 < NT) {
      if (t + 2 < NT) {
        asm volatile("s_waitcnt vmcnt(%0)" ::"i"(LPT) : "memory");  // t+1 landed
      } else {
        asm volatile("s_waitcnt vmcnt(0)" ::: "memory");  // tail
      }
      __builtin_amdgcn_sched_barrier(0);
      __builtin_amdgcn_s_barrier();
    }
  }
#undef STAGE

  // epilogue
#pragma unroll
  for (int mf = 0; mf < MF; ++mf) {
#pragma unroll
    for (int nf = 0; nf < 4; ++nf) {
      int m = m0 + wm * (BMT / 2) + mf * 16 + fq * 4;
      int n = n0 + wn * 64 + nf * 16 + fr;
      if (mode == 2) {
        int b = m >> 11, t = m & (T_ - 1);
        int h = n >> 6, hd = n & 63;
        uint2 pk;
        pk.x = pack2(acc[mf][nf][0], acc[mf][nf][1]);
        pk.y = pack2(acc[mf][nf][2], acc[mf][nf][3]);
        uint16_t* dst = (uint16_t*)Out + ((((size_t)b * H_ + h) * HD_ + hd) * T_ + t);
        *(uint2*)dst = pk;
      } else if (mode == 3) {
#pragma unroll
        for (int rr = 0; rr < 4; ++rr)
          ((float*)Out)[(size_t)(m + rr) * D_ + n] = acc[mf][nf][rr];
      } else {
#pragma unroll
        for (int rr = 0; rr < 4; ++rr) {
          int mm = m + rr;
          int b = mm >> 11, t = mm & (T_ - 1);
          int h = n >> 6, hd = n & 63;
          ((uint16_t*)Out)[((((size_t)b * H_ + h) * T_ + t) << 6) + hd] =
              f2bf(acc[mf][nf][rr] * scale);
        }
      }
    }
  }
}

// ---------------- flash attention (causal), 8 waves x 32 q, 32x32 swapped ----------------
// Pair-processed kv tiles (2 per barrier interval), XCD-local per-head grid.
// Qh,Kh: [B,H,T,64] bf16 (Q pre-scaled by 0.125*log2e). Vt: [B,H,64,T] bf16.
__global__ __launch_bounds__(512)
void attn_fwd(const uint16_t* __restrict__ Qh, const uint16_t* __restrict__ Kh,
              const uint16_t* __restrict__ Vt, uint16_t* __restrict__ O) {
  // K: SB[0..3] (pair p uses 2p,2p+1), V: SB[4..7]. 64 KB.
  __shared__ __align__(16) uint16_t SB[8][64 * 64];

  const int tid = threadIdx.x, wid = tid >> 6, lane = tid & 63;
  const int ql = lane & 31, hi = lane >> 5;
  const int bid = blockIdx.x;
  // decode: bid = ((7-qb)*8 + (bh>>3))*8 + (bh&7)  -> same-bh blocks share XCD,
  // longest (largest qb) dispatched first.
  const int x = bid & 7;
  const int e = bid >> 3;
  const int qb = 7 - (e >> 3);
  const int bh = ((e & 7) << 3) | x;
  const int q0 = qb * 256;
  const int wq0 = q0 + wid * 32;  // this wave's first q row
  const size_t hoff = (size_t)bh * T_ * HD_;
  const uint16_t* Qp = Qh + hoff;
  const uint16_t* Kp = Kh + hoff;
  const uint16_t* Vp = Vt + hoff;

  // Q fragments (B-operand): lane owns q-row (wq0+ql); k = hd = ks*16 + hi*8 + j
  bf16x8 qf[4];
  {
    const uint16_t* qrow = Qp + (size_t)(wq0 + ql) * 64 + hi * 8;
#pragma unroll
    for (int ks = 0; ks < 4; ++ks) qf[ks] = *(const bf16x8*)(qrow + ks * 16);
  }

  float m = -1e30f, l = 0.f;
  f32x16 acc[2];  // O^T: row = hd = mo*32 + (r&3)+8*(r>>2)+4*hi, col = q = ql
#pragma unroll
  for (int mo = 0; mo < 2; ++mo)
#pragma unroll
    for (int r = 0; r < 16; ++r) acc[mo][r] = 0.f;

  const int npairs = 2 * qb + 2;  // 2 tiles per pair, = ntiles/2 exactly

#define STAGE(buf, t)                                                        \
  do {                                                                       \
    int row = wid * 8 + (lane >> 3);                                         \
    int sw = ((lane & 7) ^ (row & 7)) << 3;                                  \
    gll16(Kp + (size_t)((t) * 64 + row) * 64 + sw, &SB[buf][wid * 512]);     \
    gll16(Vp + (size_t)row * T_ + (t) * 64 + sw, &SB[4 + (buf)][wid * 512]); \
  } while (0)

  STAGE(0, 0);
  STAGE(1, 1);
  asm volatile("s_waitcnt vmcnt(0)" ::: "memory");
  __builtin_amdgcn_s_barrier();

  for (int j = 0; j < npairs; ++j) {
    const int pb = (j & 1) * 2;
    if (j + 1 < npairs) {
      const int nb = ((j + 1) & 1) * 2;
      STAGE(nb, 2 * j + 2);
      STAGE(nb + 1, 2 * j + 3);
    }

#pragma unroll
    for (int s = 0; s < 2; ++s) {
      const int it = 2 * j + s;
      if (it * 64 <= wq0 + 31) {  // wave active unless whole tile above diagonal
        const uint16_t* Kl = &SB[pb + s][0];
        const uint16_t* Vl = &SB[4 + pb + s][0];
        // S^T = K @ Q : col = q (lane-local), rows = kv
        f32x16 st[2];
#pragma unroll
        for (int mm = 0; mm < 2; ++mm)
#pragma unroll
          for (int r = 0; r < 16; ++r) st[mm][r] = 0.f;
        __builtin_amdgcn_s_setprio(1);
#pragma unroll
        for (int ks = 0; ks < 4; ++ks) {
#pragma unroll
          for (int mm = 0; mm < 2; ++mm) {
            int row = mm * 32 + ql;
            int ch = (ks * 2 + hi) ^ (row & 7);
            bf16x8 kf = *(const bf16x8*)&Kl[row * 64 + ch * 8];
            st[mm] = __builtin_amdgcn_mfma_f32_32x32x16_bf16(kf, qf[ks], st[mm], 0, 0, 0);
          }
        }
        __builtin_amdgcn_s_setprio(0);

        // causal mask (diagonal-straddling tiles only)
        if (it * 64 + 63 > wq0) {
          int qg = wq0 + ql;
#pragma unroll
          for (int mm = 0; mm < 2; ++mm)
#pragma unroll
            for (int r = 0; r < 16; ++r) {
              int kv = it * 64 + mm * 32 + (r & 3) + 8 * (r >> 2) + 4 * hi;
              if (kv > qg) st[mm][r] = -1e30f;
            }
        }

        // row max: 32 in-lane + pair lane
        float pm = st[0][0];
#pragma unroll
        for (int r = 1; r < 16; ++r) pm = fmaxf(pm, st[0][r]);
#pragma unroll
        for (int r = 0; r < 16; ++r) pm = fmaxf(pm, st[1][r]);
        pm = fmaxf(pm, __shfl_xor(pm, 32));

        // defer-max rescale (THR = 8 in log2 domain)
        if (__any(pm > m + 8.f)) {
          float mn = fmaxf(m, pm);
          float sf = exp2a(m - mn);
          m = mn;
          l *= sf;
#pragma unroll
          for (int mo = 0; mo < 2; ++mo)
#pragma unroll
            for (int r = 0; r < 16; ++r) acc[mo][r] *= sf;
        }

        // P = exp2(S - m), row sum
        float rs = 0.f;
#pragma unroll
        for (int mm = 0; mm < 2; ++mm)
#pragma unroll
          for (int r = 0; r < 16; ++r) {
            float p = exp2a(st[mm][r] - m);
            st[mm][r] = p;
            rs += p;
          }
        rs += __shfl_xor(rs, 32);
        l += rs;

        // P -> bf16 B-frags in-register (cvt_pk + permlane32_swap)
        bf16x8 pf[4];
#pragma unroll
        for (int mm = 0; mm < 2; ++mm)
#pragma unroll
          for (int g = 0; g < 2; ++g) {
            uint32_t a1 = cvtpk(st[mm][8 * g + 0], st[mm][8 * g + 1]);
            uint32_t a2 = cvtpk(st[mm][8 * g + 2], st[mm][8 * g + 3]);
            uint32_t b1 = cvtpk(st[mm][8 * g + 4], st[mm][8 * g + 5]);
            uint32_t b2 = cvtpk(st[mm][8 * g + 6], st[mm][8 * g + 7]);
            plswap(a1, b1);
            plswap(a2, b2);
            union { uint32_t w[4]; bf16x8 v; } u;
            u.w[0] = a1; u.w[1] = a2; u.w[2] = b1; u.w[3] = b2;
            pf[mm * 2 + g] = u.v;
          }

        // O^T += V^T @ P^T
        __builtin_amdgcn_s_setprio(1);
#pragma unroll
        for (int ks = 0; ks < 4; ++ks) {
#pragma unroll
          for (int mo = 0; mo < 2; ++mo) {
            int row = mo * 32 + ql;
            int ch = (ks * 2 + hi) ^ (row & 7);
            bf16x8 vf = *(const bf16x8*)&Vl[row * 64 + ch * 8];
            acc[mo] = __builtin_amdgcn_mfma_f32_32x32x16_bf16(vf, pf[ks], acc[mo], 0, 0, 0);
          }
        }
        __builtin_amdgcn_s_setprio(0);
      }
    }

    if (j + 1 < npairs) {
      asm volatile("s_waitcnt vmcnt(0)" ::: "memory");  // next pair landed
      __builtin_amdgcn_s_barrier();
    }
  }
#undef STAGE

  // epilogue: O^T -> LDS (transpose, swizzled) -> coalesced global store
  __syncthreads();
  uint16_t* ost = &SB[0][0];  // 256 rows x 64 cols
  {
    float inv = 1.0f / l;
    uint16_t* wst = ost + wid * 2048;
#pragma unroll
    for (int mo = 0; mo < 2; ++mo)
#pragma unroll
      for (int r = 0; r < 16; r += 2) {
        int hd = mo * 32 + (r & 3) + 8 * (r >> 2) + 4 * hi;
        uint32_t pk = pack2(acc[mo][r] * inv, acc[mo][r + 1] * inv);
        int col = hd ^ ((ql & 7) << 3);
        *(uint32_t*)&wst[ql * 64 + col] = pk;
      }
  }
  __syncthreads();
  {
    int row = tid >> 1, half = tid & 1;
    int r7 = row & 7;
    int b = bh >> 4, h = bh & 15;
    size_t g = (size_t)(b * T_ + q0 + row) * D_ + h * 64 + half * 32;
#pragma unroll
    for (int j2 = 0; j2 < 4; ++j2) {
      int cc = half * 4 + j2;
      uint4 val = *(const uint4*)&ost[row * 64 + (cc ^ r7) * 8];
      *(uint4*)&O[g + j2 * 8] = val;
    }
  }
}

// ---------------- launcher ----------------
extern "C" void kernel_launch(void* const* d_in, const int* in_sizes, int n_in,
                              void* d_out, int out_size, void* d_ws, size_t ws_size,
                              hipStream_t stream) {
  (void)in_sizes; (void)n_in; (void)out_size; (void)ws_size;
  const float* q  = (const float*)d_in[0];
  const float* k  = (const float*)d_in[1];
  const float* v  = (const float*)d_in[2];
  // d_in[3] = mask (causal; structure hardcoded)
  const float* Wq = (const float*)d_in[4];
  const float* Wk = (const float*)d_in[5];
  const float* Wv = (const float*)d_in[6];
  const float* Wo = (const float*)d_in[7];

  uint8_t* ws = (uint8_t*)d_ws;
  const size_t MB = 1u << 20;
  uint16_t* WQB = (uint16_t*)(ws + 0 * MB);
  uint16_t* WKB = (uint16_t*)(ws + 2 * MB);
  uint16_t* WVB = (uint16_t*)(ws + 4 * MB);
  uint16_t* WOB = (uint16_t*)(ws + 6 * MB);
  uint16_t* XQ  = (uint16_t*)(ws + 8 * MB);
  uint16_t* XK  = (uint16_t*)(ws + 24 * MB);
  uint16_t* XV  = (uint16_t*)(ws + 40 * MB);
  uint16_t* QH  = (uint16_t*)(ws + 56 * MB);
  uint16_t* KH  = (uint16_t*)(ws + 72 * MB);
  uint16_t* VT  = (uint16_t*)(ws + 88 * MB);
  uint16_t* AC  = (uint16_t*)(ws + 8 * MB);  // alias XQ (dead after QKV gemm)

  const int nBig = B_ * T_ * D_;   // 8388608
  cvt3<<<dim3(nBig / 2048, 3), 256, 0, stream>>>(q, k, v, XQ, XK, XV);
  cvtW<<<dim3(D_ * D_ / 2048, 4), 256, 0, stream>>>(Wq, Wk, Wv, Wo, WQB, WKB, WVB, WOB);

  // Q scale = HD^-0.5 * log2(e) -> softmax in exp2 domain
  const float qscale = 0.125f * 1.44269504088896340736f;

  // fused QKV projections: 3 x 128 blocks of 256x256
  gemm256<256><<<dim3(384), 512, 0, stream>>>(XQ, XK, XV, WQB, WKB, WVB,
                                              QH, KH, VT, 0, qscale);

  attn_fwd<<<dim3(512), 512, 0, stream>>>(QH, KH, VT, AC);

  // output projection: 256 blocks of 128x256, fp32 out
  gemm256<128><<<dim3(256), 512, 0, stream>>>(AC, nullptr, nullptr,
                                              WOB, nullptr, nullptr,
                                              d_out, nullptr, nullptr, 3, 1.0f);
}

// Round 9
// 165.831 us; speedup vs baseline: 1.0696x; 1.0696x over previous
//
#include <hip/hip_runtime.h>
#include <stdint.h>

#define B_  4
#define T_  2048
#define D_  1024
#define H_  16
#define HD_ 64
#define KK_ 1024

typedef __bf16 bf16_t;
typedef __bf16 bf16x8 __attribute__((ext_vector_type(8)));
typedef float  f32x4  __attribute__((ext_vector_type(4)));
typedef float  f32x16 __attribute__((ext_vector_type(16)));

__device__ __forceinline__ uint16_t f2bf(float f) {
  uint32_t x = __float_as_uint(f);
  uint32_t r = (x + 0x7fffu + ((x >> 16) & 1u)) >> 16;
  return (uint16_t)r;
}

__device__ __forceinline__ uint32_t pack2(float a, float b) {
  return (uint32_t)f2bf(a) | ((uint32_t)f2bf(b) << 16);
}

__device__ __forceinline__ float exp2a(float x) {
  float r;
  asm("v_exp_f32 %0, %1" : "=v"(r) : "v"(x));
  return r;
}

__device__ __forceinline__ uint32_t cvtpk(float a, float b) {
  uint32_t r;
  asm("v_cvt_pk_bf16_f32 %0, %1, %2" : "=v"(r) : "v"(a), "v"(b));
  return r;
}

__device__ __forceinline__ void plswap(uint32_t& a, uint32_t& b) {
  asm("v_permlane32_swap_b32 %0, %1" : "+v"(a), "+v"(b));
}

// async 16B global->LDS; lds dst is wave-uniform base (+lane*16 by HW)
__device__ __forceinline__ void gll16(const void* g, void* l) {
  __builtin_amdgcn_global_load_lds(
      (const __attribute__((address_space(1))) void*)g,
      (__attribute__((address_space(3))) void*)l, 16, 0, 0);
}

// ---------------- fp32 -> bf16 conversion (weights only) ----------------
__global__ __launch_bounds__(256) void cvtW(const float* __restrict__ s0,
                                            const float* __restrict__ s1,
                                            const float* __restrict__ s2,
                                            const float* __restrict__ s3,
                                            uint16_t* __restrict__ d0,
                                            uint16_t* __restrict__ d1,
                                            uint16_t* __restrict__ d2,
                                            uint16_t* __restrict__ d3) {
  const float* in = blockIdx.y == 0 ? s0 : (blockIdx.y == 1 ? s1 :
                    (blockIdx.y == 2 ? s2 : s3));
  uint16_t* out = blockIdx.y == 0 ? d0 : (blockIdx.y == 1 ? d1 :
                  (blockIdx.y == 2 ? d2 : d3));
  int i = (blockIdx.x * 256 + threadIdx.x) * 8;
  float4 a = *(const float4*)(in + i);
  float4 b = *(const float4*)(in + i + 4);
  uint4 u;
  u.x = pack2(a.x, a.y);
  u.y = pack2(a.z, a.w);
  u.z = pack2(b.x, b.y);
  u.w = pack2(b.z, b.w);
  *(uint4*)(out + i) = u;
}

// ---------------- deep-pipelined GEMM: C = A[M,K] @ W[N,K]^T ----------------
// BM=128, BN=256, BK=64, 8 waves (2M x 4N), 64x64 per wave. R5 structure:
// 3 LDS buffers, stage-2-ahead, counted vmcnt, compiler-interleaved frag reads.
// AF32: A is fp32 in HBM; 2-tile-distance register pipeline: tile t ISSUES
// fp32 loads for A(t+2) into regs, and at end of tile t converts+ds_writes
// A(t+1) (loaded one full tile ago -> latency hidden). B via global_load_lds.
// mode 0: Q -> bf16 [B,H,T,64] scaled; 1: K same; 2: V -> [B,H,64,T]; 3: fp32.
template <bool AF32>
__global__ __launch_bounds__(512, 2)
void gemm8(const void* __restrict__ a0, const void* __restrict__ a1,
           const void* __restrict__ a2, const uint16_t* __restrict__ w0,
           const uint16_t* __restrict__ w1, const uint16_t* __restrict__ w2,
           void* __restrict__ o0, void* __restrict__ o1, void* __restrict__ o2,
           int mode_base, float scale0) {
  __shared__ __align__(16) uint16_t Ab[3][128 * 64];  // 48 KB
  __shared__ __align__(16) uint16_t Bb[3][256 * 64];  // 96 KB

  const int nwg = gridDim.x;
  const int bid = blockIdx.x;
  const int cpx = nwg >> 3;                       // nwg % 8 == 0
  const int swz = (bid & 7) * cpx + (bid >> 3);   // XCD-contiguous chunks
  const int g = swz >> 8;                         // 256 blocks per gemm
  const int r = swz & 255;
  const int mt = r >> 2, nt = r & 3;
  const int m0 = mt * 128, n0 = nt * 256;

  const void* A = g == 0 ? a0 : (g == 1 ? a1 : a2);
  const uint16_t* W = g == 0 ? w0 : (g == 1 ? w1 : w2);
  void* Out = g == 0 ? o0 : (g == 1 ? o1 : o2);
  const int mode = mode_base + g;
  const float scale = (mode == 0) ? scale0 : 1.0f;
  const float* A32 = (const float*)A;
  const uint16_t* A16 = (const uint16_t*)A;

  const int tid = threadIdx.x;
  const int wid = tid >> 6, lane = tid & 63;
  const int fr = lane & 15, fq = lane >> 4;
  const int wm = wid >> 2, wn = wid & 3;
  const int srow = lane >> 3, c8 = lane & 7;

  f32x4 acc[4][4];
#pragma unroll
  for (int i = 0; i < 4; ++i)
#pragma unroll
    for (int j = 0; j < 4; ++j) acc[i][j] = (f32x4){0.f, 0.f, 0.f, 0.f};

  const int NT = KK_ / 64;  // 16 tiles (even -> unroll-2 parity works)
  float4 axA[4], axB[4];    // two in-flight fp32 A reg sets (AF32 only)

  // LDS row = 64 elems (8 chunks of 8); LDS[row][j] = src[row][j ^ (row&7)].
  // A rows for this wave: c*64 + wid*8 + srow, c in {0,1}.
#define ALOAD(ax, t)                                                          \
  do {                                                                        \
    _Pragma("unroll")                                                         \
    for (int c = 0; c < 2; ++c) {                                             \
      int row = c * 64 + wid * 8 + srow;                                      \
      int sw = (c8 ^ (row & 7)) << 3;                                         \
      const float* src = A32 + (size_t)(m0 + row) * KK_ + (t) * 64 + sw;      \
      ax[c * 2] = *(const float4*)src;                                        \
      ax[c * 2 + 1] = *(const float4*)(src + 4);                              \
    }                                                                         \
  } while (0)

#define AWRITE(bi, ax)                                                        \
  do {                                                                        \
    _Pragma("unroll")                                                         \
    for (int c = 0; c < 2; ++c) {                                             \
      uint4 u;                                                                \
      u.x = cvtpk(ax[c * 2].x, ax[c * 2].y);                                  \
      u.y = cvtpk(ax[c * 2].z, ax[c * 2].w);                                  \
      u.z = cvtpk(ax[c * 2 + 1].x, ax[c * 2 + 1].y);                          \
      u.w = cvtpk(ax[c * 2 + 1].z, ax[c * 2 + 1].w);                          \
      *(uint4*)&Ab[bi][c * 4096 + wid * 512 + srow * 64 + c8 * 8] = u;        \
    }                                                                         \
  } while (0)

#define STAGEA16(bi, t)                                                       \
  do {                                                                        \
    _Pragma("unroll")                                                         \
    for (int c = 0; c < 2; ++c) {                                             \
      int row = c * 64 + wid * 8 + srow;                                      \
      int sw = (c8 ^ (row & 7)) << 3;                                         \
      gll16(A16 + (size_t)(m0 + row) * KK_ + (t) * 64 + sw,                   \
            &Ab[bi][c * 4096 + wid * 512]);                                   \
    }                                                                         \
  } while (0)

#define STAGEB(bi, t)                                                         \
  do {                                                                        \
    _Pragma("unroll")                                                         \
    for (int c = 0; c < 4; ++c) {                                             \
      int row = c * 64 + wid * 8 + srow;                                      \
      int sw = (c8 ^ (row & 7)) << 3;                                         \
      gll16(W + (size_t)(n0 + row) * KK_ + (t) * 64 + sw,                     \
            &Bb[bi][c * 4096 + wid * 512]);                                   \
    }                                                                         \
  } while (0)

  // ---- prologue ----
  if (AF32) {
    ALOAD(axA, 0);       // A0 -> regs
    STAGEB(0, 0);
    AWRITE(0, axA);      // compiler inserts vmcnt for axA deps
    ALOAD(axA, 1);       // A1 -> regs (written at end of t=0)
    STAGEB(1, 1);
    asm volatile("s_waitcnt vmcnt(8)" ::: "memory");  // B0 done; A1,B1 flying
  } else {
    STAGEA16(0, 0);
    STAGEB(0, 0);
    STAGEA16(1, 1);
    STAGEB(1, 1);
    asm volatile("s_waitcnt vmcnt(6)" ::: "memory");  // tile0 done; tile1 flying
  }
  asm volatile("s_waitcnt lgkmcnt(0)" ::: "memory");
  __builtin_amdgcn_s_barrier();

  // ---- main loop, unrolled x2 so the A reg-set parity is static ----
  // BODY(t): frag reads from buf cur; issue t+2 staging (A->axL regs if AF32);
  // MFMAs; end-of-tile: AWRITE A(t+1) from axU, counted vmcnt, barrier.
#define BODY(t, axU, axL)                                                     \
  do {                                                                        \
    const uint16_t* Ac = &Ab[cur][0];                                         \
    const uint16_t* Bc = &Bb[cur][0];                                         \
    int nb = cur + 2; if (nb >= 3) nb -= 3;                                   \
    bf16x8 af0[4], bf0[4], af1[4], bf1[4];                                    \
    _Pragma("unroll")                                                         \
    for (int i = 0; i < 4; ++i) {                                             \
      int ra = wm * 64 + i * 16 + fr;                                         \
      af0[i] = *(const bf16x8*)&Ac[ra * 64 + ((fq ^ (ra & 7)) << 3)];         \
      int rb = wn * 64 + i * 16 + fr;                                         \
      bf0[i] = *(const bf16x8*)&Bc[rb * 64 + ((fq ^ (rb & 7)) << 3)];         \
    }                                                                         \
    if ((t) + 2 < NT) {                                                       \
      if (AF32) { ALOAD(axL, (t) + 2); } else { STAGEA16(nb, (t) + 2); }      \
      STAGEB(nb, (t) + 2);                                                    \
    }                                                                         \
    _Pragma("unroll")                                                         \
    for (int i = 0; i < 4; ++i) {                                             \
      int ra = wm * 64 + i * 16 + fr;                                         \
      af1[i] = *(const bf16x8*)&Ac[ra * 64 + (((4 + fq) ^ (ra & 7)) << 3)];   \
      int rb = wn * 64 + i * 16 + fr;                                         \
      bf1[i] = *(const bf16x8*)&Bc[rb * 64 + (((4 + fq) ^ (rb & 7)) << 3)];   \
    }                                                                         \
    __builtin_amdgcn_s_setprio(1);                                            \
    _Pragma("unroll")                                                         \
    for (int mf = 0; mf < 4; ++mf)                                            \
      _Pragma("unroll")                                                       \
      for (int nf = 0; nf < 4; ++nf)                                          \
        acc[mf][nf] = __builtin_amdgcn_mfma_f32_16x16x32_bf16(                \
            af0[mf], bf0[nf], acc[mf][nf], 0, 0, 0);                          \
    _Pragma("unroll")                                                         \
    for (int mf = 0; mf < 4; ++mf)                                            \
      _Pragma("unroll")                                                       \
      for (int nf = 0; nf < 4; ++nf)                                          \
        acc[mf][nf] = __builtin_amdgcn_mfma_f32_16x16x32_bf16(                \
            af1[mf], bf1[nf], acc[mf][nf], 0, 0, 0);                          \
    __builtin_amdgcn_s_setprio(0);                                            \
    if ((t) + 1 < NT) {                                                       \
      int wb = cur + 1; if (wb >= 3) wb -= 3;                                 \
      if (AF32) AWRITE(wb, axU); /* A(t+1) -> LDS; regs 1 tile old */         \
      if ((t) + 2 < NT) {                                                     \
        asm volatile("s_waitcnt vmcnt(%0)" ::"i"(AF32 ? 8 : 6) : "memory");   \
      } else {                                                                \
        asm volatile("s_waitcnt vmcnt(0)" ::: "memory");                      \
      }                                                                       \
      asm volatile("s_waitcnt lgkmcnt(0)" ::: "memory");                      \
      __builtin_amdgcn_s_barrier();                                           \
    }                                                                         \
    ++cur; if (cur == 3) cur = 0;                                             \
  } while (0)

  int cur = 0;
  for (int tt = 0; tt < NT; tt += 2) {
    BODY(tt, axA, axB);
    BODY(tt + 1, axB, axA);
  }
#undef BODY
#undef ALOAD
#undef AWRITE
#undef STAGEA16
#undef STAGEB

  // epilogue
#pragma unroll
  for (int mf = 0; mf < 4; ++mf) {
#pragma unroll
    for (int nf = 0; nf < 4; ++nf) {
      int m = m0 + wm * 64 + mf * 16 + fq * 4;
      int n = n0 + wn * 64 + nf * 16 + fr;
      if (mode == 2) {
        int b = m >> 11, t = m & (T_ - 1);
        int h = n >> 6, hd = n & 63;
        uint2 pk;
        pk.x = pack2(acc[mf][nf][0], acc[mf][nf][1]);
        pk.y = pack2(acc[mf][nf][2], acc[mf][nf][3]);
        uint16_t* dst = (uint16_t*)Out + ((((size_t)b * H_ + h) * HD_ + hd) * T_ + t);
        *(uint2*)dst = pk;
      } else if (mode == 3) {
#pragma unroll
        for (int rr = 0; rr < 4; ++rr)
          ((float*)Out)[(size_t)(m + rr) * D_ + n] = acc[mf][nf][rr];
      } else {
#pragma unroll
        for (int rr = 0; rr < 4; ++rr) {
          int mm = m + rr;
          int b = mm >> 11, t = mm & (T_ - 1);
          int h = n >> 6, hd = n & 63;
          ((uint16_t*)Out)[((((size_t)b * H_ + h) * T_ + t) << 6) + hd] =
              f2bf(acc[mf][nf][rr] * scale);
        }
      }
    }
  }
}

// ---------------- flash attention (causal), 8 waves x 32 q, 32x32 swapped ----------------
// (R5 version: triple-buffered K/V, counted vmcnt(2), longest-first grid.)
// Qh,Kh: [B,H,T,64] bf16 (Q pre-scaled by 0.125*log2e). Vt: [B,H,64,T] bf16.
__global__ __launch_bounds__(512)
void attn_fwd(const uint16_t* __restrict__ Qh, const uint16_t* __restrict__ Kh,
              const uint16_t* __restrict__ Vt, uint16_t* __restrict__ O) {
  // SB[0..2] = K triple buffer, SB[3..5] = V triple buffer (48 KB).
  __shared__ __align__(16) uint16_t SB[6][64 * 64];

  const int tid = threadIdx.x, wid = tid >> 6, lane = tid & 63;
  const int ql = lane & 31, hi = lane >> 5;
  const int bid = blockIdx.x;
  const int qb = (T_ / 256 - 1) - (bid >> 6);  // longest blocks first
  const int bh = bid & 63;
  const int q0 = qb * 256;
  const int wq0 = q0 + wid * 32;  // this wave's first q row
  const size_t hoff = (size_t)bh * T_ * HD_;
  const uint16_t* Qp = Qh + hoff;
  const uint16_t* Kp = Kh + hoff;
  const uint16_t* Vp = Vt + hoff;

  // Q fragments (B-operand): lane owns q-row (wq0+ql); k = hd = ks*16 + hi*8 + j
  bf16x8 qf[4];
  {
    const uint16_t* qrow = Qp + (size_t)(wq0 + ql) * 64 + hi * 8;
#pragma unroll
    for (int ks = 0; ks < 4; ++ks) qf[ks] = *(const bf16x8*)(qrow + ks * 16);
  }

  float m = -1e30f, l = 0.f;
  f32x16 acc[2];  // O^T: row = hd = mo*32 + (r&3)+8*(r>>2)+4*hi, col = q = ql
#pragma unroll
  for (int mo = 0; mo < 2; ++mo)
#pragma unroll
    for (int r = 0; r < 16; ++r) acc[mo][r] = 0.f;

  const int ntiles = 4 * qb + 4;

#define STAGE(buf, t)                                                        \
  do {                                                                       \
    int row = wid * 8 + (lane >> 3);                                         \
    int sw = ((lane & 7) ^ (row & 7)) << 3;                                  \
    gll16(Kp + (size_t)((t) * 64 + row) * 64 + sw, &SB[buf][wid * 512]);     \
    gll16(Vp + (size_t)row * T_ + (t) * 64 + sw, &SB[3 + (buf)][wid * 512]); \
  } while (0)

  STAGE(0, 0);
  if (ntiles > 1) STAGE(1, 1);
  asm volatile("s_waitcnt vmcnt(2)" ::: "memory");
  __builtin_amdgcn_s_barrier();

  int cur = 0;
  for (int it = 0; it < ntiles; ++it) {
    if (it + 2 < ntiles) {
      int nb = cur + 2; if (nb >= 3) nb -= 3;
      STAGE(nb, it + 2);
    }

    if (it * 64 <= wq0 + 31) {  // wave active unless whole tile above diagonal
      // S^T = K @ Q : col = q (lane-local), rows = kv
      f32x16 st[2];
#pragma unroll
      for (int mm = 0; mm < 2; ++mm)
#pragma unroll
        for (int r = 0; r < 16; ++r) st[mm][r] = 0.f;
#pragma unroll
      for (int ks = 0; ks < 4; ++ks) {
#pragma unroll
        for (int mm = 0; mm < 2; ++mm) {
          int row = mm * 32 + ql;
          int ch = (ks * 2 + hi) ^ (row & 7);
          bf16x8 kf = *(const bf16x8*)&SB[cur][row * 64 + ch * 8];
          st[mm] = __builtin_amdgcn_mfma_f32_32x32x16_bf16(kf, qf[ks], st[mm], 0, 0, 0);
        }
      }

      // causal mask (diagonal-straddling tiles only)
      if (it * 64 + 63 > wq0) {
        int qg = wq0 + ql;
#pragma unroll
        for (int mm = 0; mm < 2; ++mm)
#pragma unroll
          for (int r = 0; r < 16; ++r) {
            int kv = it * 64 + mm * 32 + (r & 3) + 8 * (r >> 2) + 4 * hi;
            if (kv > qg) st[mm][r] = -1e30f;
          }
      }

      // row max: 32 in-lane + pair lane
      float pm = st[0][0];
#pragma unroll
      for (int r = 1; r < 16; ++r) pm = fmaxf(pm, st[0][r]);
#pragma unroll
      for (int r = 0; r < 16; ++r) pm = fmaxf(pm, st[1][r]);
      pm = fmaxf(pm, __shfl_xor(pm, 32));

      // defer-max rescale (THR = 8 in log2 domain)
      if (__any(pm > m + 8.f)) {
        float mn = fmaxf(m, pm);
        float sf = exp2a(m - mn);
        m = mn;
        l *= sf;
#pragma unroll
        for (int mo = 0; mo < 2; ++mo)
#pragma unroll
          for (int r = 0; r < 16; ++r) acc[mo][r] *= sf;
      }

      // P = exp2(S - m), row sum
      float rs = 0.f;
#pragma unroll
      for (int mm = 0; mm < 2; ++mm)
#pragma unroll
        for (int r = 0; r < 16; ++r) {
          float p = exp2a(st[mm][r] - m);
          st[mm][r] = p;
          rs += p;
        }
      rs += __shfl_xor(rs, 32);
      l += rs;

      // P -> bf16 B-frags in-register (cvt_pk + permlane32_swap)
      bf16x8 pf[4];
#pragma unroll
      for (int mm = 0; mm < 2; ++mm)
#pragma unroll
        for (int g = 0; g < 2; ++g) {
          uint32_t a1 = cvtpk(st[mm][8 * g + 0], st[mm][8 * g + 1]);
          uint32_t a2 = cvtpk(st[mm][8 * g + 2], st[mm][8 * g + 3]);
          uint32_t b1 = cvtpk(st[mm][8 * g + 4], st[mm][8 * g + 5]);
          uint32_t b2 = cvtpk(st[mm][8 * g + 6], st[mm][8 * g + 7]);
          plswap(a1, b1);
          plswap(a2, b2);
          union { uint32_t w[4]; bf16x8 v; } u;
          u.w[0] = a1; u.w[1] = a2; u.w[2] = b1; u.w[3] = b2;
          pf[mm * 2 + g] = u.v;
        }

      // O^T += V^T @ P^T
#pragma unroll
      for (int ks = 0; ks < 4; ++ks) {
#pragma unroll
        for (int mo = 0; mo < 2; ++mo) {
          int row = mo * 32 + ql;
          int ch = (ks * 2 + hi) ^ (row & 7);
          bf16x8 vf = *(const bf16x8*)&SB[3 + cur][row * 64 + ch * 8];
          acc[mo] = __builtin_amdgcn_mfma_f32_32x32x16_bf16(vf, pf[ks], acc[mo], 0, 0, 0);
        }
      }
    }

    if (it + 1 < ntiles) {
      if (it + 2 < ntiles) {
        asm volatile("s_waitcnt vmcnt(2)" ::: "memory");  // it+1 landed, it+2 flying
      } else {
        asm volatile("s_waitcnt vmcnt(0)" ::: "memory");  // tail
      }
      __builtin_amdgcn_s_barrier();
    }
    ++cur; if (cur == 3) cur = 0;
  }
#undef STAGE

  // epilogue: O^T -> LDS (transpose, swizzled) -> coalesced global store
  __syncthreads();
  uint16_t* ost = &SB[0][0];  // 256 rows x 64 cols
  {
    float inv = 1.0f / l;
    uint16_t* wst = ost + wid * 2048;
#pragma unroll
    for (int mo = 0; mo < 2; ++mo)
#pragma unroll
      for (int r = 0; r < 16; r += 2) {
        int hd = mo * 32 + (r & 3) + 8 * (r >> 2) + 4 * hi;
        uint32_t pk = pack2(acc[mo][r] * inv, acc[mo][r + 1] * inv);
        int col = hd ^ ((ql & 7) << 3);
        *(uint32_t*)&wst[ql * 64 + col] = pk;
      }
  }
  __syncthreads();
  {
    int row = tid >> 1, half = tid & 1;
    int r7 = row & 7;
    int b = bh >> 4, h = bh & 15;
    size_t g = (size_t)(b * T_ + q0 + row) * D_ + h * 64 + half * 32;
#pragma unroll
    for (int j2 = 0; j2 < 4; ++j2) {
      int cc = half * 4 + j2;
      uint4 val = *(const uint4*)&ost[row * 64 + (cc ^ r7) * 8];
      *(uint4*)&O[g + j2 * 8] = val;
    }
  }
}

// ---------------- launcher ----------------
extern "C" void kernel_launch(void* const* d_in, const int* in_sizes, int n_in,
                              void* d_out, int out_size, void* d_ws, size_t ws_size,
                              hipStream_t stream) {
  (void)in_sizes; (void)n_in; (void)out_size; (void)ws_size;
  const float* q  = (const float*)d_in[0];
  const float* k  = (const float*)d_in[1];
  const float* v  = (const float*)d_in[2];
  // d_in[3] = mask (causal; structure hardcoded)
  const float* Wq = (const float*)d_in[4];
  const float* Wk = (const float*)d_in[5];
  const float* Wv = (const float*)d_in[6];
  const float* Wo = (const float*)d_in[7];

  uint8_t* ws = (uint8_t*)d_ws;
  const size_t MB = 1u << 20;
  uint16_t* WQB = (uint16_t*)(ws + 0 * MB);
  uint16_t* WKB = (uint16_t*)(ws + 2 * MB);
  uint16_t* WVB = (uint16_t*)(ws + 4 * MB);
  uint16_t* WOB = (uint16_t*)(ws + 6 * MB);
  uint16_t* QH  = (uint16_t*)(ws + 56 * MB);
  uint16_t* KH  = (uint16_t*)(ws + 72 * MB);
  uint16_t* VT  = (uint16_t*)(ws + 88 * MB);
  uint16_t* AC  = (uint16_t*)(ws + 8 * MB);

  // weights fp32 -> bf16 (tiny)
  cvtW<<<dim3(D_ * D_ / 2048, 4), 256, 0, stream>>>(Wq, Wk, Wv, Wo, WQB, WKB, WVB, WOB);

  // Q scale = HD^-0.5 * log2(e) -> softmax in exp2 domain
  const float qscale = 0.125f * 1.44269504088896340736f;

  // fused QKV projections (fp32 A, in-kernel convert): 3 x 256 blocks
  gemm8<true><<<dim3(768), 512, 0, stream>>>(q, k, v, WQB, WKB, WVB,
                                             QH, KH, VT, 0, qscale);

  attn_fwd<<<dim3(T_ / 256 * 64), 512, 0, stream>>>(QH, KH, VT, AC);

  // output projection (bf16 A from attention): 256 blocks, fp32 out
  gemm8<false><<<dim3(256), 512, 0, stream>>>(AC, nullptr, nullptr,
                                              WOB, nullptr, nullptr,
                                              d_out, nullptr, nullptr, 3, 1.0f);
}